// Round 10
// baseline (399.418 us; speedup 1.0000x reference)
//
#include <hip/hip_runtime.h>
#include <math.h>

#define EPSF 1e-12f

// N=64, C=512, P=1600, K=64
// R12: k2g Wb -> LDS staging (kills the 64x16B-granule-per-instr Wb loads,
// ~8x the request count of the R10-optimized x stream).
//   k0 : Wb[k][c] = bf16(W); zeros asum.
//   k2g: GEMM1 + softmax + a_t (R10 pair-tile float2). R12: Wb staged once
//        per block into LDS (64 KB, XOR-swizzle col^((row&7)*8) -> uniform
//        8 lanes/slot b128 reads); inner loop uses ds_read_b128 instead of
//        4 scattered global loads per kc. x path / softmax / a_t byte-identical.
//   k3g: GEMM2 slot-permuted full-K direct store (R11-verified, CONTROL).
//   k4 : merged one-pass epilogue (R8-verified).
// ws: a_t bf16 @0 (13,107,200) | Wb @13,107,200 | asum @13,172,736

typedef short bf16x8 __attribute__((ext_vector_type(8)));
typedef float f32x4  __attribute__((ext_vector_type(4)));

__device__ __forceinline__ ushort f2b(float x) {
    unsigned u = __float_as_uint(x);
    return (ushort)((u + 0x7fffu + ((u >> 16) & 1u)) >> 16);
}

// ------------------------------------------------- K0: Wb[k][c] = bf16(W), asum=0
__global__ __launch_bounds__(256) void k0_wb(const float* __restrict__ W,
                                             ushort* __restrict__ Wb,
                                             float* __restrict__ asum) {
    int i = blockIdx.x * 256 + threadIdx.x;
    if (i < 64 * 512) Wb[i] = f2b(W[i]);
    if (i < 64 * 64) asum[i] = 0.f;
}

// ------------------------------------------------- K2g: GEMM1 + softmax + a_t
// grid (25 ptiles of 64, 64 n), 128 thr = 2 waves x 32 p. Wave: two D[16p][64k]
// tiles (even/odd p interleave), K=512 c.  [R10-verified + R12 Wb-LDS]
__global__ __launch_bounds__(128) void k2g_gemm1(const float* __restrict__ x,
                                                 const ushort* __restrict__ Wb,
                                                 ushort* __restrict__ a_t,
                                                 float* __restrict__ asum) {
    const int n = blockIdx.y;
    const int p0 = blockIdx.x * 64;
    const int wv = threadIdx.x >> 6, lane = threadIdx.x & 63;
    const int q = lane >> 4, l15 = lane & 15;
    const int pw = p0 + wv * 32;

    // R12: stage Wb (64 KB bf16) into LDS, XOR-swizzled so the b128 fragment
    // reads put 8 lanes on each 16-B slot across all 32 banks.
    __shared__ ushort wlds[64 * 512];
    {
        const int t = threadIdx.x;            // 0..127: row t/2, half (t&1)*256
        const int row = t >> 1, half = (t & 1) * 256;
        const int sw = (row & 7) * 8;
        #pragma unroll
        for (int i = 0; i < 32; i++) {
            const int col = half + i * 8;
            bf16x8 w = *(const bf16x8*)(Wb + row * 512 + col);
            *(bf16x8*)&wlds[row * 512 + (col ^ sw)] = w;
        }
    }
    __syncthreads();

    // float2 source: x[n][c = kc*32 + q*8 + j][pw + 2*l15 (+1)]
    const float* xq = x + (size_t)n * 819200 + (size_t)q * 8 * 1600 + pw + 2 * l15;
    const int swb = (l15 & 7) * 8;            // read-side swizzle (row&7 == l15&7)

    f32x4 acce[4] = {}, acco[4] = {};
    float sspe = 0.f, sspo = 0.f;

    // 2-deep software pipeline on x loads (statically indexed via full unroll).
    float2 fv[2][8];
    #pragma unroll
    for (int j = 0; j < 8; j++) fv[0][j] = *(const float2*)(xq + (size_t)j * 1600);

    #pragma unroll
    for (int kc = 0; kc < 16; kc++) {
        const int cur = kc & 1, nxt = cur ^ 1;
        if (kc < 15) {
            #pragma unroll
            for (int j = 0; j < 8; j++)
                fv[nxt][j] = *(const float2*)(xq + (size_t)((kc + 1) * 32 + j) * 1600);
        }
        bf16x8 afe, afo;
        #pragma unroll
        for (int j = 0; j < 8; j++) {
            float fe = fv[cur][j].x, fo = fv[cur][j].y;
            sspe = fmaf(fe, fe, sspe);          // fp32-accurate sum of squares
            sspo = fmaf(fo, fo, sspo);
            afe[j] = (short)f2b(fe);
            afo[j] = (short)f2b(fo);
        }
        #pragma unroll
        for (int nt = 0; nt < 4; nt++) {
            bf16x8 bw = *(const bf16x8*)&wlds[(nt * 16 + l15) * 512
                                              + ((kc * 32 + q * 8) ^ swb)];
            acce[nt] = __builtin_amdgcn_mfma_f32_16x16x32_bf16(afe, bw, acce[nt], 0, 0, 0);
            acco[nt] = __builtin_amdgcn_mfma_f32_16x16x32_bf16(afo, bw, acco[nt], 0, 0, 0);
        }
    }

    // complete ss across the 4 q-lanes sharing p-row l15 (per tile)
    sspe += __shfl_xor(sspe, 16, 64);
    sspe += __shfl_xor(sspe, 32, 64);
    sspo += __shfl_xor(sspo, 16, 64);
    sspo += __shfl_xor(sspo, 32, 64);
    float rne_l = 1.f / fmaxf(sqrtf(sspe), EPSF);
    float rno_l = 1.f / fmaxf(sqrtf(sspo), EPSF);
    float rnve[4], rnvo[4];
    #pragma unroll
    for (int r = 0; r < 4; r++) {
        rnve[r] = __shfl(rne_l, q * 4 + r, 64);  // rn for D-row q*4+r (even tile)
        rnvo[r] = __shfl(rno_l, q * 4 + r, 64);  // odd tile
    }

    // softmax over k (4 nt in-lane x 16 l15 cross-lane)  [R1/R3-verified, x2 tiles]
    float ve[4][4], vo[4][4];
    float mxe[4] = {-3.4e38f, -3.4e38f, -3.4e38f, -3.4e38f};
    float mxo[4] = {-3.4e38f, -3.4e38f, -3.4e38f, -3.4e38f};
    #pragma unroll
    for (int nt = 0; nt < 4; nt++)
        #pragma unroll
        for (int r = 0; r < 4; r++) {
            ve[nt][r] = acce[nt][r] * rnve[r];
            vo[nt][r] = acco[nt][r] * rnvo[r];
            mxe[r] = fmaxf(mxe[r], ve[nt][r]);
            mxo[r] = fmaxf(mxo[r], vo[nt][r]);
        }
    #pragma unroll
    for (int s = 1; s <= 8; s <<= 1)
        #pragma unroll
        for (int r = 0; r < 4; r++) {
            mxe[r] = fmaxf(mxe[r], __shfl_xor(mxe[r], s, 64));
            mxo[r] = fmaxf(mxo[r], __shfl_xor(mxo[r], s, 64));
        }
    float sme[4] = {0.f, 0.f, 0.f, 0.f}, smo[4] = {0.f, 0.f, 0.f, 0.f};
    #pragma unroll
    for (int nt = 0; nt < 4; nt++)
        #pragma unroll
        for (int r = 0; r < 4; r++) {
            ve[nt][r] = __expf(ve[nt][r] - mxe[r]); sme[r] += ve[nt][r];
            vo[nt][r] = __expf(vo[nt][r] - mxo[r]); smo[r] += vo[nt][r];
        }
    #pragma unroll
    for (int s = 1; s <= 8; s <<= 1)
        #pragma unroll
        for (int r = 0; r < 4; r++) {
            sme[r] += __shfl_xor(sme[r], s, 64);
            smo[r] += __shfl_xor(smo[r], s, 64);
        }
    float inve[4], invo[4];
    #pragma unroll
    for (int r = 0; r < 4; r++) { inve[r] = 1.f / sme[r]; invo[r] = 1.f / smo[r]; }
    #pragma unroll
    for (int nt = 0; nt < 4; nt++)
        #pragma unroll
        for (int r = 0; r < 4; r++) { ve[nt][r] *= inve[r]; vo[nt][r] *= invo[r]; }

    // asum partials: column k = nt*16 + l15, sum over this wave's 32 p-rows
    #pragma unroll
    for (int nt = 0; nt < 4; nt++) {
        float t = ve[nt][0] + ve[nt][1] + ve[nt][2] + ve[nt][3]
                + vo[nt][0] + vo[nt][1] + vo[nt][2] + vo[nt][3];
        t += __shfl_xor(t, 16, 64);
        t += __shfl_xor(t, 32, 64);
        if (lane < 16) atomicAdd(&asum[n * 64 + nt * 16 + lane], t);
    }

    // a' = a*rn -> bf16, LDS bounce [k][slot 0..31] (pad 36), global b128 write.
    // a_t stored in MFMA slot order (R11-verified):
    //   slot q*8+j  <->  p_local (j<4 ? q*4+j : 16+q*4+j-4)
    __shared__ ushort abuf[2][64 * 36];
    #pragma unroll
    for (int nt = 0; nt < 4; nt++)
        #pragma unroll
        for (int r = 0; r < 4; r++) {
            const int ple = 2 * (q * 4 + r);
            const int plo = ple + 1;
            const int se = (ple < 16) ? ((ple >> 2) * 8 + (ple & 3))
                                      : (((ple - 16) >> 2) * 8 + ((ple - 16) & 3) + 4);
            const int so = (plo < 16) ? ((plo >> 2) * 8 + (plo & 3))
                                      : (((plo - 16) >> 2) * 8 + ((plo - 16) & 3) + 4);
            abuf[wv][(nt * 16 + l15) * 36 + se] = f2b(ve[nt][r] * rnve[r]);
            abuf[wv][(nt * 16 + l15) * 36 + so] = f2b(vo[nt][r] * rnvo[r]);
        }
    __syncthreads();
    ushort* dst = a_t + ((size_t)n * 64 + lane) * 1600 + pw;
    const ushort* srcl = &abuf[wv][lane * 36];
    *(uint4*)(dst)      = *(const uint4*)(srcl);
    *(uint4*)(dst + 8)  = *(const uint4*)(srcl + 8);
    *(uint4*)(dst + 16) = *(const uint4*)(srcl + 16);
    *(uint4*)(dst + 24) = *(const uint4*)(srcl + 24);
}

// ------------------------------------------------- K3g: GEMM2  [R11-verified, CONTROL]
// D[k][c]: block 64k x 128c, full K=1600 p. grid 256 linear, 512 thr = 8 waves.
// B-frag slot (q,j) holds x[c][pc + (j<4 ? q*4+j : 16+q*4+j-4)]:
//   f0 = float4 @ pc+q*4, f1 = float4 @ pc+16+q*4 -> 64-B segments across q.
// A-frag: a_t is slot-ordered (written by k2g) -> contiguous b128.
__global__ __launch_bounds__(512) void k3_gemm2(const ushort* __restrict__ a_t,
                                                const float* __restrict__ x,
                                                float* __restrict__ out) {
    const int id = blockIdx.x;
    const int xcd = id & 7, slot = id >> 3;
    const int ct = slot & 3, ng = slot >> 2;
    const int n = ng * 8 + xcd;
    const int c0 = ct * 128;
    const int wv = threadIdx.x >> 6, lane = threadIdx.x & 63;
    const int q = lane >> 4, l15 = lane & 15;
    const int cw = c0 + wv * 16;

    const ushort* abase = a_t + ((size_t)n * 64 + l15) * 1600 + q * 8;
    const float*  xrow  = x + ((size_t)n * 512 + cw + l15) * 1600;

    f32x4 acc[4] = {};
    #pragma unroll 2
    for (int pc = 0; pc < 1600; pc += 32) {
        bf16x8 af[4];
        #pragma unroll
        for (int mt = 0; mt < 4; mt++)
            af[mt] = *(const bf16x8*)(abase + (size_t)mt * 16 * 1600 + pc);
        const float* xr = xrow + pc;
        float4 f0 = *(const float4*)(xr + q * 4);
        float4 f1 = *(const float4*)(xr + 16 + q * 4);
        bf16x8 b;
        b[0] = (short)f2b(f0.x); b[1] = (short)f2b(f0.y);
        b[2] = (short)f2b(f0.z); b[3] = (short)f2b(f0.w);
        b[4] = (short)f2b(f1.x); b[5] = (short)f2b(f1.y);
        b[6] = (short)f2b(f1.z); b[7] = (short)f2b(f1.w);
        #pragma unroll
        for (int mt = 0; mt < 4; mt++)
            acc[mt] = __builtin_amdgcn_mfma_f32_16x16x32_bf16(af[mt], b, acc[mt], 0, 0, 0);
    }
    // D row = k = mt*16 + q*4 + r, col = c = cw + l15. Sole owner -> plain store.
    float* ob = out + (size_t)n * 32768 + cw + l15;
    #pragma unroll
    for (int mt = 0; mt < 4; mt++)
        #pragma unroll
        for (int r = 0; r < 4; r++)
            ob[(mt * 16 + q * 4 + r) * 512] = acc[mt][r];
}

// ------------------------------------------------- K4: merged one-pass epilogue
// per-n block: read raw slab, subtract asum*cent, rownorm2, gn, normalize, write.
__global__ __launch_bounds__(512) void k4(const float* __restrict__ vraw,
                                          const float* __restrict__ asum,
                                          const float* __restrict__ cent,
                                          float* __restrict__ out) {
    const int n = blockIdx.x;
    const int wv = threadIdx.x >> 6, lane = threadIdx.x & 63;
    __shared__ float stash[64 * 512];
    __shared__ float rs[64];
    __shared__ float gsh;

    #pragma unroll
    for (int i = 0; i < 8; i++) {
        const int k = wv * 8 + i;
        const size_t ro = (size_t)n * 32768 + (size_t)k * 512 + lane * 8;
        const float as = asum[n * 64 + k];
        const f32x4* pp = (const f32x4*)(vraw + ro);
        f32x4 a0 = pp[0], a1 = pp[1];
        const f32x4* cp = (const f32x4*)(cent + k * 512 + lane * 8);
        f32x4 v0 = a0 - cp[0] * as;
        f32x4 v1 = a1 - cp[1] * as;
        float s = 0.f;
        #pragma unroll
        for (int e = 0; e < 4; e++) { s = fmaf(v0[e], v0[e], s); s = fmaf(v1[e], v1[e], s); }
        *(f32x4*)&stash[k * 512 + lane * 8] = v0;
        *(f32x4*)&stash[k * 512 + lane * 8 + 4] = v1;
        #pragma unroll
        for (int off = 32; off > 0; off >>= 1) s += __shfl_down(s, off, 64);
        if (lane == 0) rs[k] = s;
    }
    __syncthreads();
    if (wv == 0) {
        float t = rs[lane];
        float d = fmaxf(sqrtf(t), EPSF);
        float r = t / (d * d);
        #pragma unroll
        for (int off = 32; off > 0; off >>= 1) r += __shfl_down(r, off, 64);
        if (lane == 0) gsh = fmaxf(sqrtf(r), EPSF);
    }
    __syncthreads();
    const float g = gsh;
    #pragma unroll
    for (int i = 0; i < 8; i++) {
        const int k = wv * 8 + i;
        const float inv = 1.f / (fmaxf(sqrtf(rs[k]), EPSF) * g);
        f32x4 v0 = *(const f32x4*)&stash[k * 512 + lane * 8];
        f32x4 v1 = *(const f32x4*)&stash[k * 512 + lane * 8 + 4];
        v0 *= inv;
        v1 *= inv;
        float* op = out + (size_t)n * 32768 + (size_t)k * 512 + lane * 8;
        *(f32x4*)op = v0;
        *(f32x4*)(op + 4) = v1;
    }
}

// -------------------------------------------------
extern "C" void kernel_launch(void* const* d_in, const int* in_sizes, int n_in,
                              void* d_out, int out_size, void* d_ws, size_t ws_size,
                              hipStream_t stream) {
    const float* x    = (const float*)d_in[0];
    const float* W    = (const float*)d_in[1];
    const float* cent = (const float*)d_in[2];
    float* out = (float*)d_out;
    char* ws = (char*)d_ws;

    ushort* a_t  = (ushort*)(ws + 0);
    ushort* Wb   = (ushort*)(ws + 13107200);
    float*  asum = (float*)(ws + 13172736);

    hipLaunchKernelGGL(k0_wb,     dim3(128),    dim3(256), 0, stream, W, Wb, asum);
    hipLaunchKernelGGL(k2g_gemm1, dim3(25, 64), dim3(128), 0, stream, x, Wb, a_t, asum);
    hipLaunchKernelGGL(k3_gemm2,  dim3(256),    dim3(512), 0, stream, a_t, x, out);
    hipLaunchKernelGGL(k4,        dim3(64),     dim3(512), 0, stream, out, asum, cent, out);
}

// Round 12
// 381.220 us; speedup vs baseline: 1.0477x; 1.0477x over previous
//
#include <hip/hip_runtime.h>
#include <math.h>

#define EPSF 1e-12f

// N=64, C=512, P=1600, K=64
// R13-retry (R11 round failed in infra; source re-audited: no OOB, no graph
// violation, bit-identical operands vs R11 — resubmitting unchanged).
// k2g Wb de-gather WITHOUT LDS: k0 packs W into MFMA SLOT ORDER
// Wp[kc][nt][lane][8] -> each bwv load is one coalesced 1 KB instruction
// (16 line-req vs 64), L2-resident (64 KB shared by all 1600 blocks), zero
// LDS, zero occupancy cost. k2g is the R11 structure otherwise.
//   k0 : Wp[((kc*4+nt)*64+lane)*8+e] = bf16(W[(nt*16+(lane&15))*512
//                                             + kc*32+(lane>>4)*8+e]); asum=0.
//   k2g: GEMM1 + softmax + a_t (R10 pair-tile float2 + R11 slot-order a_t).
//   k3g: GEMM2 slot-permuted full-K direct store (R11-verified, CONTROL).
//   k4 : merged one-pass epilogue (R8-verified).
// ws: a_t bf16 @0 (13,107,200) | Wp @13,107,200 (65,536) | asum @13,172,736

typedef short bf16x8 __attribute__((ext_vector_type(8)));
typedef float f32x4  __attribute__((ext_vector_type(4)));

__device__ __forceinline__ ushort f2b(float x) {
    unsigned u = __float_as_uint(x);
    return (ushort)((u + 0x7fffu + ((u >> 16) & 1u)) >> 16);
}

// ------------------------------------------------- K0: Wp = bf16(W) slot-packed, asum=0
__global__ __launch_bounds__(256) void k0_wb(const float* __restrict__ W,
                                             ushort* __restrict__ Wp,
                                             float* __restrict__ asum) {
    int o = blockIdx.x * 256 + threadIdx.x;
    if (o < 64 * 512) {
        const int e    = o & 7;
        const int lane = (o >> 3) & 63;
        const int g    = o >> 9;           // kc*4 + nt
        const int nt   = g & 3, kc = g >> 2;
        const int row  = nt * 16 + (lane & 15);
        const int col  = kc * 32 + (lane >> 4) * 8 + e;
        Wp[o] = f2b(W[row * 512 + col]);
    }
    if (o < 64 * 64) asum[o] = 0.f;
}

// ------------------------------------------------- K2g: GEMM1 + softmax + a_t
// grid (25 ptiles of 64, 64 n), 128 thr = 2 waves x 32 p. Wave: two D[16p][64k]
// tiles (even/odd p interleave), K=512 c.  [R11 structure + R13 packed-Wp loads]
__global__ __launch_bounds__(128) void k2g_gemm1(const float* __restrict__ x,
                                                 const ushort* __restrict__ Wp,
                                                 ushort* __restrict__ a_t,
                                                 float* __restrict__ asum) {
    const int n = blockIdx.y;
    const int p0 = blockIdx.x * 64;
    const int wv = threadIdx.x >> 6, lane = threadIdx.x & 63;
    const int q = lane >> 4, l15 = lane & 15;
    const int pw = p0 + wv * 32;

    // float2 source: x[n][c = kc*32 + q*8 + j][pw + 2*l15 (+1)]
    // 16 lanes x 8 B = 128-B segment per c-row (full lines, half the requests).
    const float* xq = x + (size_t)n * 819200 + (size_t)q * 8 * 1600 + pw + 2 * l15;
    // Packed Wb: fragment for (kc,nt) at Wp + ((kc*4+nt)*64 + lane)*8 — one
    // coalesced 1 KB load per instruction, L2-resident.
    const ushort* wl = Wp + (size_t)lane * 8;

    f32x4 acce[4] = {}, acco[4] = {};
    float sspe = 0.f, sspo = 0.f;

    // 2-deep software pipeline (statically indexed via full unroll).
    float2 fv[2][8];
    bf16x8 bwv[2][4];
    #pragma unroll
    for (int j = 0; j < 8; j++) fv[0][j] = *(const float2*)(xq + (size_t)j * 1600);
    #pragma unroll
    for (int nt = 0; nt < 4; nt++) bwv[0][nt] = *(const bf16x8*)(wl + (size_t)nt * 512);

    #pragma unroll
    for (int kc = 0; kc < 16; kc++) {
        const int cur = kc & 1, nxt = cur ^ 1;
        if (kc < 15) {
            #pragma unroll
            for (int j = 0; j < 8; j++)
                fv[nxt][j] = *(const float2*)(xq + (size_t)((kc + 1) * 32 + j) * 1600);
            #pragma unroll
            for (int nt = 0; nt < 4; nt++)
                bwv[nxt][nt] = *(const bf16x8*)(wl + (size_t)((kc + 1) * 4 + nt) * 512);
        }
        bf16x8 afe, afo;
        #pragma unroll
        for (int j = 0; j < 8; j++) {
            float fe = fv[cur][j].x, fo = fv[cur][j].y;
            sspe = fmaf(fe, fe, sspe);          // fp32-accurate sum of squares
            sspo = fmaf(fo, fo, sspo);
            afe[j] = (short)f2b(fe);
            afo[j] = (short)f2b(fo);
        }
        #pragma unroll
        for (int nt = 0; nt < 4; nt++) {
            acce[nt] = __builtin_amdgcn_mfma_f32_16x16x32_bf16(afe, bwv[cur][nt], acce[nt], 0, 0, 0);
            acco[nt] = __builtin_amdgcn_mfma_f32_16x16x32_bf16(afo, bwv[cur][nt], acco[nt], 0, 0, 0);
        }
    }

    // complete ss across the 4 q-lanes sharing p-row l15 (per tile)
    sspe += __shfl_xor(sspe, 16, 64);
    sspe += __shfl_xor(sspe, 32, 64);
    sspo += __shfl_xor(sspo, 16, 64);
    sspo += __shfl_xor(sspo, 32, 64);
    float rne_l = 1.f / fmaxf(sqrtf(sspe), EPSF);
    float rno_l = 1.f / fmaxf(sqrtf(sspo), EPSF);
    float rnve[4], rnvo[4];
    #pragma unroll
    for (int r = 0; r < 4; r++) {
        rnve[r] = __shfl(rne_l, q * 4 + r, 64);  // rn for D-row q*4+r (even tile)
        rnvo[r] = __shfl(rno_l, q * 4 + r, 64);  // odd tile
    }

    // softmax over k (4 nt in-lane x 16 l15 cross-lane)  [R1/R3-verified, x2 tiles]
    float ve[4][4], vo[4][4];
    float mxe[4] = {-3.4e38f, -3.4e38f, -3.4e38f, -3.4e38f};
    float mxo[4] = {-3.4e38f, -3.4e38f, -3.4e38f, -3.4e38f};
    #pragma unroll
    for (int nt = 0; nt < 4; nt++)
        #pragma unroll
        for (int r = 0; r < 4; r++) {
            ve[nt][r] = acce[nt][r] * rnve[r];
            vo[nt][r] = acco[nt][r] * rnvo[r];
            mxe[r] = fmaxf(mxe[r], ve[nt][r]);
            mxo[r] = fmaxf(mxo[r], vo[nt][r]);
        }
    #pragma unroll
    for (int s = 1; s <= 8; s <<= 1)
        #pragma unroll
        for (int r = 0; r < 4; r++) {
            mxe[r] = fmaxf(mxe[r], __shfl_xor(mxe[r], s, 64));
            mxo[r] = fmaxf(mxo[r], __shfl_xor(mxo[r], s, 64));
        }
    float sme[4] = {0.f, 0.f, 0.f, 0.f}, smo[4] = {0.f, 0.f, 0.f, 0.f};
    #pragma unroll
    for (int nt = 0; nt < 4; nt++)
        #pragma unroll
        for (int r = 0; r < 4; r++) {
            ve[nt][r] = __expf(ve[nt][r] - mxe[r]); sme[r] += ve[nt][r];
            vo[nt][r] = __expf(vo[nt][r] - mxo[r]); smo[r] += vo[nt][r];
        }
    #pragma unroll
    for (int s = 1; s <= 8; s <<= 1)
        #pragma unroll
        for (int r = 0; r < 4; r++) {
            sme[r] += __shfl_xor(sme[r], s, 64);
            smo[r] += __shfl_xor(smo[r], s, 64);
        }
    float inve[4], invo[4];
    #pragma unroll
    for (int r = 0; r < 4; r++) { inve[r] = 1.f / sme[r]; invo[r] = 1.f / smo[r]; }
    #pragma unroll
    for (int nt = 0; nt < 4; nt++)
        #pragma unroll
        for (int r = 0; r < 4; r++) { ve[nt][r] *= inve[r]; vo[nt][r] *= invo[r]; }

    // asum partials: column k = nt*16 + l15, sum over this wave's 32 p-rows
    #pragma unroll
    for (int nt = 0; nt < 4; nt++) {
        float t = ve[nt][0] + ve[nt][1] + ve[nt][2] + ve[nt][3]
                + vo[nt][0] + vo[nt][1] + vo[nt][2] + vo[nt][3];
        t += __shfl_xor(t, 16, 64);
        t += __shfl_xor(t, 32, 64);
        if (lane < 16) atomicAdd(&asum[n * 64 + nt * 16 + lane], t);
    }

    // a' = a*rn -> bf16, LDS bounce [k][slot 0..31] (pad 36), global b128 write.
    // a_t stored in MFMA slot order (R11-verified):
    //   slot q*8+j  <->  p_local (j<4 ? q*4+j : 16+q*4+j-4)
    __shared__ ushort abuf[2][64 * 36];
    #pragma unroll
    for (int nt = 0; nt < 4; nt++)
        #pragma unroll
        for (int r = 0; r < 4; r++) {
            const int ple = 2 * (q * 4 + r);
            const int plo = ple + 1;
            const int se = (ple < 16) ? ((ple >> 2) * 8 + (ple & 3))
                                      : (((ple - 16) >> 2) * 8 + ((ple - 16) & 3) + 4);
            const int so = (plo < 16) ? ((plo >> 2) * 8 + (plo & 3))
                                      : (((plo - 16) >> 2) * 8 + ((plo - 16) & 3) + 4);
            abuf[wv][(nt * 16 + l15) * 36 + se] = f2b(ve[nt][r] * rnve[r]);
            abuf[wv][(nt * 16 + l15) * 36 + so] = f2b(vo[nt][r] * rnvo[r]);
        }
    __syncthreads();
    ushort* dst = a_t + ((size_t)n * 64 + lane) * 1600 + pw;
    const ushort* srcl = &abuf[wv][lane * 36];
    *(uint4*)(dst)      = *(const uint4*)(srcl);
    *(uint4*)(dst + 8)  = *(const uint4*)(srcl + 8);
    *(uint4*)(dst + 16) = *(const uint4*)(srcl + 16);
    *(uint4*)(dst + 24) = *(const uint4*)(srcl + 24);
}

// ------------------------------------------------- K3g: GEMM2  [R11-verified, CONTROL]
// D[k][c]: block 64k x 128c, full K=1600 p. grid 256 linear, 512 thr = 8 waves.
// B-frag slot (q,j) holds x[c][pc + (j<4 ? q*4+j : 16+q*4+j-4)]:
//   f0 = float4 @ pc+q*4, f1 = float4 @ pc+16+q*4 -> 64-B segments across q.
// A-frag: a_t is slot-ordered (written by k2g) -> contiguous b128.
__global__ __launch_bounds__(512) void k3_gemm2(const ushort* __restrict__ a_t,
                                                const float* __restrict__ x,
                                                float* __restrict__ out) {
    const int id = blockIdx.x;
    const int xcd = id & 7, slot = id >> 3;
    const int ct = slot & 3, ng = slot >> 2;
    const int n = ng * 8 + xcd;
    const int c0 = ct * 128;
    const int wv = threadIdx.x >> 6, lane = threadIdx.x & 63;
    const int q = lane >> 4, l15 = lane & 15;
    const int cw = c0 + wv * 16;

    const ushort* abase = a_t + ((size_t)n * 64 + l15) * 1600 + q * 8;
    const float*  xrow  = x + ((size_t)n * 512 + cw + l15) * 1600;

    f32x4 acc[4] = {};
    #pragma unroll 2
    for (int pc = 0; pc < 1600; pc += 32) {
        bf16x8 af[4];
        #pragma unroll
        for (int mt = 0; mt < 4; mt++)
            af[mt] = *(const bf16x8*)(abase + (size_t)mt * 16 * 1600 + pc);
        const float* xr = xrow + pc;
        float4 f0 = *(const float4*)(xr + q * 4);
        float4 f1 = *(const float4*)(xr + 16 + q * 4);
        bf16x8 b;
        b[0] = (short)f2b(f0.x); b[1] = (short)f2b(f0.y);
        b[2] = (short)f2b(f0.z); b[3] = (short)f2b(f0.w);
        b[4] = (short)f2b(f1.x); b[5] = (short)f2b(f1.y);
        b[6] = (short)f2b(f1.z); b[7] = (short)f2b(f1.w);
        #pragma unroll
        for (int mt = 0; mt < 4; mt++)
            acc[mt] = __builtin_amdgcn_mfma_f32_16x16x32_bf16(af[mt], b, acc[mt], 0, 0, 0);
    }
    // D row = k = mt*16 + q*4 + r, col = c = cw + l15. Sole owner -> plain store.
    float* ob = out + (size_t)n * 32768 + cw + l15;
    #pragma unroll
    for (int mt = 0; mt < 4; mt++)
        #pragma unroll
        for (int r = 0; r < 4; r++)
            ob[(mt * 16 + q * 4 + r) * 512] = acc[mt][r];
}

// ------------------------------------------------- K4: merged one-pass epilogue
// per-n block: read raw slab, subtract asum*cent, rownorm2, gn, normalize, write.
__global__ __launch_bounds__(512) void k4(const float* __restrict__ vraw,
                                          const float* __restrict__ asum,
                                          const float* __restrict__ cent,
                                          float* __restrict__ out) {
    const int n = blockIdx.x;
    const int wv = threadIdx.x >> 6, lane = threadIdx.x & 63;
    __shared__ float stash[64 * 512];
    __shared__ float rs[64];
    __shared__ float gsh;

    #pragma unroll
    for (int i = 0; i < 8; i++) {
        const int k = wv * 8 + i;
        const size_t ro = (size_t)n * 32768 + (size_t)k * 512 + lane * 8;
        const float as = asum[n * 64 + k];
        const f32x4* pp = (const f32x4*)(vraw + ro);
        f32x4 a0 = pp[0], a1 = pp[1];
        const f32x4* cp = (const f32x4*)(cent + k * 512 + lane * 8);
        f32x4 v0 = a0 - cp[0] * as;
        f32x4 v1 = a1 - cp[1] * as;
        float s = 0.f;
        #pragma unroll
        for (int e = 0; e < 4; e++) { s = fmaf(v0[e], v0[e], s); s = fmaf(v1[e], v1[e], s); }
        *(f32x4*)&stash[k * 512 + lane * 8] = v0;
        *(f32x4*)&stash[k * 512 + lane * 8 + 4] = v1;
        #pragma unroll
        for (int off = 32; off > 0; off >>= 1) s += __shfl_down(s, off, 64);
        if (lane == 0) rs[k] = s;
    }
    __syncthreads();
    if (wv == 0) {
        float t = rs[lane];
        float d = fmaxf(sqrtf(t), EPSF);
        float r = t / (d * d);
        #pragma unroll
        for (int off = 32; off > 0; off >>= 1) r += __shfl_down(r, off, 64);
        if (lane == 0) gsh = fmaxf(sqrtf(r), EPSF);
    }
    __syncthreads();
    const float g = gsh;
    #pragma unroll
    for (int i = 0; i < 8; i++) {
        const int k = wv * 8 + i;
        const float inv = 1.f / (fmaxf(sqrtf(rs[k]), EPSF) * g);
        f32x4 v0 = *(const f32x4*)&stash[k * 512 + lane * 8];
        f32x4 v1 = *(const f32x4*)&stash[k * 512 + lane * 8 + 4];
        v0 *= inv;
        v1 *= inv;
        float* op = out + (size_t)n * 32768 + (size_t)k * 512 + lane * 8;
        *(f32x4*)op = v0;
        *(f32x4*)(op + 4) = v1;
    }
}

// -------------------------------------------------
extern "C" void kernel_launch(void* const* d_in, const int* in_sizes, int n_in,
                              void* d_out, int out_size, void* d_ws, size_t ws_size,
                              hipStream_t stream) {
    const float* x    = (const float*)d_in[0];
    const float* W    = (const float*)d_in[1];
    const float* cent = (const float*)d_in[2];
    float* out = (float*)d_out;
    char* ws = (char*)d_ws;

    ushort* a_t  = (ushort*)(ws + 0);
    ushort* Wp   = (ushort*)(ws + 13107200);
    float*  asum = (float*)(ws + 13172736);

    hipLaunchKernelGGL(k0_wb,     dim3(128),    dim3(256), 0, stream, W, Wp, asum);
    hipLaunchKernelGGL(k2g_gemm1, dim3(25, 64), dim3(128), 0, stream, x, Wp, a_t, asum);
    hipLaunchKernelGGL(k3_gemm2,  dim3(256),    dim3(512), 0, stream, a_t, x, out);
    hipLaunchKernelGGL(k4,        dim3(64),     dim3(512), 0, stream, out, asum, cent, out);
}